// Round 9
// baseline (588.086 us; speedup 1.0000x reference)
//
#include <hip/hip_runtime.h>
#include <hip/hip_fp16.h>

typedef unsigned short u16;
typedef unsigned int u32;
typedef float f32x4 __attribute__((ext_vector_type(4)));
typedef _Float16 half8 __attribute__((ext_vector_type(8)));
typedef unsigned short u16x4 __attribute__((ext_vector_type(4)));

#define CDIM 768
#define NP 1024
#define NB 32

static constexpr size_t CHW = (size_t)NB * CDIM * NP;  // 25,165,824

// workspace layout (bytes)
static constexpr size_t XT_OFF  = 0;                         // f16 [b][p][c]; later reused as aoT f16
static constexpr size_t HS_OFF  = CHW * 2;                   // f16 hs11, hs111
static constexpr size_t WHI_OFF = HS_OFF + CHW * 4;          // f16 weights

__device__ __forceinline__ u16 f16bits(float f) {
  return __half_as_ushort(__float2half_rn(f));
}
__device__ __forceinline__ float f16tof(u16 b) {
  __half_raw hr; hr.x = b; return __half2float(__half(hr));
}
__device__ __forceinline__ u32 pk2(u32 p, float a, float b) {
  float x = f16tof((u16)(p & 0xffff)) + a;
  float y = f16tof((u16)(p >> 16)) + b;
  return (u32)f16bits(x) | ((u32)f16bits(y) << 16);
}

typedef __attribute__((address_space(1))) void gv_t;
typedef __attribute__((address_space(3))) void lv_t;
__device__ __forceinline__ void gload_lds16(const void* g, void* l) {
  __builtin_amdgcn_global_load_lds((gv_t*)g, (lv_t*)l, 16, 0, 0);
}

// ---------------- cast W (fp32 -> f16) ----------------
__global__ __launch_bounds__(256) void cast_w_k(const float* __restrict__ W,
                                                u16* __restrict__ hi) {
  int i = blockIdx.x * 256 + threadIdx.x;
  float4 v = ((const float4*)W)[i];
  u16x4 h4 = {f16bits(v.x), f16bits(v.y), f16bits(v.z), f16bits(v.w)};
  ((u16x4*)hi)[i] = h4;
}

// ---------------- transpose + f16 cast: src fp32 [b][c][p] -> dst f16 [b][p][c] ----------------
__global__ __launch_bounds__(256) void transpose_f16_k(const float* __restrict__ src,
                                                       u16* __restrict__ dxt) {
  __shared__ float tle[32][33];
  const int b = blockIdx.z, c0 = blockIdx.y * 32, p0 = blockIdx.x * 32;
  const int tid = threadIdx.x;
  const int lr = tid >> 5, lc = tid & 31;
  const float* s = src + ((size_t)b * CDIM + c0) * NP + p0;
#pragma unroll
  for (int it = 0; it < 4; ++it) {
    int c = it * 8 + lr;
    tle[c][lc] = s[(size_t)c * NP + lc];
  }
  __syncthreads();
#pragma unroll
  for (int it = 0; it < 4; ++it) {
    int p = it * 8 + lr;
    float v = tle[lc][p];
    size_t off = ((size_t)b * NP + p0 + p) * CDIM + c0 + lc;
    dxt[off] = f16bits(v);
  }
}

// ---------------- spatial permutations ----------------
__device__ __forceinline__ int sigma_fn(int mode, int z, int t, int p) {
  if (t == 0 || mode == 1) return p;
  int i = p >> 5, j = p & 31;
  if (z == 0) {
    if (t == 1) return (j << 5) | (31 - i);
    if (t == 2) return ((31 - i) << 5) | (31 - j);
    return ((31 - j) << 5) | i;
  } else {
    int ib = i & 16, jb = j & 16, il = i & 15, jl = j & 15;
    if (t == 1) return ((ib | jl) << 5) | (jb | (15 - il));
    if (t == 2) return ((ib | (15 - il)) << 5) | (jb | (15 - jl));
    return ((ib | (15 - jl)) << 5) | (jb | il);
  }
}

// ---------------- 256x256 m201-style multi-term f16 GEMM ----------------
// 512 threads = 8 waves (2M x 4N), wave tile 128x64. K-tile = 64 channels.
// LDS: 2 buffers x { A [256 rows][8 chunks of 8 u16] 32KB | B same 32KB } = 128KB + bias.
// Proven XOR geometry: phys chunk = logical ^ (row&7); staging = linear dest + swizzled src.
// Per K-tile: 4 quadrant phases (mh,nh), each {12 ds_read; 1 slice stage (2 gload_lds);
// barrier; lgkm0; setprio1; 8 MFMA (kh0); 6 reads kh1; lgkm0; 8 MFMA (kh1); setprio0; barrier}.
// vmcnt(0) only at K-tile boundary. racc packed f16x2 (NTERMS>1).
template <int OUTF16, int NTERMS>
__global__ __launch_bounds__(512, 2) void gemm_p(
    const u16* __restrict__ Whi,
    const u16* __restrict__ Bx,
    const float* __restrict__ bias, void* __restrict__ dst,
    int wselBase, int mode) {
  extern __shared__ u16 lds[];  // 2 x 32768 u16 + NTERMS*256 f32 bias
  const int tid = threadIdx.x;
  const int lane = tid & 63;
  const int w = tid >> 6;
  const int wr = w >> 2, wc = w & 3;
  const int z = blockIdx.z;
  const int did = blockIdx.x;
  const int b = (did & 7) | ((did >> 5) << 3);   // XCD clustering: same-b -> same did%8
  const int pt = (did >> 3) & 3;
  const int p0 = pt << 8;
  const int o0 = blockIdx.y << 8;
  const int l15 = lane & 15, l4 = lane >> 4;
  float* blds = (float*)(lds + 65536);

  const int NT = NTERMS * 12;

  // read bases (u16 units); frag m/n adds +1024
  int baseA[2][2], baseB[2][2];
#pragma unroll
  for (int mh = 0; mh < 2; ++mh)
#pragma unroll
    for (int kh = 0; kh < 2; ++kh)
      baseA[mh][kh] = (wr * 128 + mh * 64 + l15) * 64 + (((kh * 4 + l4) ^ (l15 & 7)) * 8);
#pragma unroll
  for (int nh = 0; nh < 2; ++nh)
#pragma unroll
    for (int kh = 0; kh < 2; ++kh)
      baseB[nh][kh] = 16384 + (wc * 64 + nh * 32 + l15) * 64 + (((kh * 4 + l4) ^ (l15 & 7)) * 8);

  // staging decode: slot d = s*1024 + it*512 + tid -> row = s*128 + it*64 + (tid>>3),
  // phys chunk = tid&7, logical = phys ^ (row&7) = (tid&7) ^ ((tid>>3)&7) (const).
  const int logc = ((tid & 7) ^ ((tid >> 3) & 7)) * 8;
  const u16* aP[4];
  const u16* bP[4];
  auto setPtrs = [&](int term) {
    int wsel = wselBase + z * 4 + term;
#pragma unroll
    for (int s = 0; s < 2; ++s)
#pragma unroll
      for (int it = 0; it < 2; ++it) {
        int row = s * 128 + it * 64 + (tid >> 3);
        aP[s * 2 + it] = Whi + ((size_t)wsel * CDIM + o0 + row) * CDIM + logc;
        int srw = sigma_fn(mode, z, term, p0 + row);
        bP[s * 2 + it] = Bx + ((size_t)b * NP + srw) * CDIM + logc;
      }
  };
  auto stageA = [&](int s, u16* lo) {
    gload_lds16(aP[s * 2 + 0], lo + (s * 1024 + tid) * 8);
    gload_lds16(aP[s * 2 + 1], lo + (s * 1024 + 512 + tid) * 8);
  };
  auto stageB = [&](int s, u16* lo) {
    gload_lds16(bP[s * 2 + 0], lo + 16384 + (s * 1024 + tid) * 8);
    gload_lds16(bP[s * 2 + 1], lo + 16384 + (s * 1024 + 512 + tid) * 8);
  };
  auto advPtrs = [&]() {
#pragma unroll
    for (int i = 0; i < 4; ++i) { aP[i] += 64; bP[i] += 64; }
  };

  // bias -> LDS
  for (int i = tid; i < NTERMS * 256; i += 512)
    blds[i] = bias[(size_t)(wselBase + z * 4 + (i >> 8)) * CDIM + o0 + (i & 255)];

  f32x4 acc[8][4];
#pragma unroll
  for (int mi = 0; mi < 8; ++mi)
#pragma unroll
    for (int ni = 0; ni < 4; ++ni) acc[mi][ni] = (f32x4){0.f, 0.f, 0.f, 0.f};
  u32 rp[8][4][2];
  if (NTERMS > 1) {
#pragma unroll
    for (int mi = 0; mi < 8; ++mi)
#pragma unroll
      for (int ni = 0; ni < 4; ++ni) { rp[mi][ni][0] = 0u; rp[mi][ni][1] = 0u; }
  }

  // prologue: stage tile 0
  setPtrs(0);
  stageA(0, lds); stageA(1, lds); stageB(0, lds); stageB(1, lds);
  if (NT > 1) advPtrs();
  asm volatile("s_waitcnt vmcnt(0)" ::: "memory");
  __builtin_amdgcn_s_barrier();
  asm volatile("" ::: "memory");

  int cur = 0;
  for (int j = 0; j < NT; ++j) {
    const u16* la = lds + cur * 32768;
    u16* lo = lds + (cur ^ 1) * 32768;
    const bool st = (j + 1) < NT;
    if (st && ((j + 1) % 12) == 0) setPtrs((j + 1) / 12);

#pragma unroll
    for (int ph = 0; ph < 4; ++ph) {
      const int mh = ph & 1, nh = ph >> 1;
      half8 af[4], bf[2];
      // kh=0 reads
#pragma unroll
      for (int m = 0; m < 4; ++m) af[m] = *(const half8*)(la + baseA[mh][0] + m * 1024);
#pragma unroll
      for (int n = 0; n < 2; ++n) bf[n] = *(const half8*)(la + baseB[nh][0] + n * 1024);
      // stage slice ph of next tile
      if (st) {
        if (ph == 0) stageA(0, lo);
        else if (ph == 1) stageA(1, lo);
        else if (ph == 2) stageB(0, lo);
        else stageB(1, lo);
      }
      __builtin_amdgcn_s_barrier();
      asm volatile("s_waitcnt lgkmcnt(0)" ::: "memory");
      __builtin_amdgcn_s_setprio(1);
#pragma unroll
      for (int m = 0; m < 4; ++m)
#pragma unroll
        for (int n = 0; n < 2; ++n)
          acc[mh * 4 + m][nh * 2 + n] =
              __builtin_amdgcn_mfma_f32_16x16x32_f16(af[m], bf[n], acc[mh * 4 + m][nh * 2 + n], 0, 0, 0);
      // kh=1 reads + MFMA
#pragma unroll
      for (int m = 0; m < 4; ++m) af[m] = *(const half8*)(la + baseA[mh][1] + m * 1024);
#pragma unroll
      for (int n = 0; n < 2; ++n) bf[n] = *(const half8*)(la + baseB[nh][1] + n * 1024);
      asm volatile("s_waitcnt lgkmcnt(0)" ::: "memory");
#pragma unroll
      for (int m = 0; m < 4; ++m)
#pragma unroll
        for (int n = 0; n < 2; ++n)
          acc[mh * 4 + m][nh * 2 + n] =
              __builtin_amdgcn_mfma_f32_16x16x32_f16(af[m], bf[n], acc[mh * 4 + m][nh * 2 + n], 0, 0, 0);
      __builtin_amdgcn_s_setprio(0);
      if (ph < 3) __builtin_amdgcn_s_barrier();
    }
    if (st) advPtrs();

    if (NTERMS > 1 && (j % 12) == 11) {  // term boundary fold into packed racc
      const int t = j / 12;
#pragma unroll
      for (int mi = 0; mi < 8; ++mi) {
        int ro = wr * 128 + mi * 16 + l4 * 4;
        float4 bv = *(const float4*)&blds[t * 256 + ro];
#pragma unroll
        for (int ni = 0; ni < 4; ++ni) {
          rp[mi][ni][0] = pk2(rp[mi][ni][0], fmaxf(0.f, acc[mi][ni][0] + bv.x),
                                             fmaxf(0.f, acc[mi][ni][1] + bv.y));
          rp[mi][ni][1] = pk2(rp[mi][ni][1], fmaxf(0.f, acc[mi][ni][2] + bv.z),
                                             fmaxf(0.f, acc[mi][ni][3] + bv.w));
          acc[mi][ni] = (f32x4){0.f, 0.f, 0.f, 0.f};
        }
      }
    }

    if (st) asm volatile("s_waitcnt vmcnt(0)" ::: "memory");
    __builtin_amdgcn_s_barrier();
    asm volatile("" ::: "memory");
    cur ^= 1;
  }

  // epilogue
#pragma unroll
  for (int mi = 0; mi < 8; ++mi) {
    int ro = o0 + wr * 128 + mi * 16 + l4 * 4;
#pragma unroll
    for (int ni = 0; ni < 4; ++ni) {
      int col = p0 + wc * 64 + ni * 16 + l15;
      size_t base = ((size_t)b * CDIM + ro) * NP + col;
      if (NTERMS > 1) {
        u16* dp = (u16*)dst + (size_t)z * CHW + base;
        dp[0 * NP] = (u16)(rp[mi][ni][0] & 0xffff);
        dp[1 * NP] = (u16)(rp[mi][ni][0] >> 16);
        dp[2 * NP] = (u16)(rp[mi][ni][1] & 0xffff);
        dp[3 * NP] = (u16)(rp[mi][ni][1] >> 16);
      } else {
        float4 bv = *(const float4*)&blds[wr * 128 + mi * 16 + l4 * 4];
        float bvf[4] = {bv.x, bv.y, bv.z, bv.w};
        float* dp = (float*)dst + (size_t)z * CHW + base;
#pragma unroll
        for (int r = 0; r < 4; ++r)
          dp[(size_t)r * NP] = fmaxf(0.f, acc[mi][ni][r] + bvf[r]);
      }
    }
  }
}

// ---------------- per-(b,c) 32x32 attention, f16 in, fused transposed-f16 output ----------------
__global__ __launch_bounds__(256) void attn_f_k(const u16* __restrict__ hs, u16* __restrict__ aoT) {
  __shared__ float q[4][1056];   // pitch 33
  __shared__ float kk[4][1056];
  const int tid = threadIdx.x, w = tid >> 6, lane = tid & 63;
  const int pair0 = blockIdx.x * 4;
  const int b = pair0 / CDIM;
  const int c0 = pair0 % CDIM;
#pragma unroll
  for (int it = 0; it < 8; ++it) {
    int d4 = it * 256 + tid;
    int pr = d4 >> 9;
    int mat = (d4 >> 8) & 1;
    int off4 = d4 & 255;
    ushort4 hv = *(const ushort4*)&hs[(size_t)mat * CHW + (size_t)(pair0 + pr) * NP + off4 * 4];
    float* dl = mat ? kk[pr] : q[pr];
    int off = off4 * 4;
    int base = (off >> 5) * 33 + (off & 31);
    dl[base] = f16tof(hv.x); dl[base + 1] = f16tof(hv.y);
    dl[base + 2] = f16tof(hv.z); dl[base + 3] = f16tof(hv.w);
  }
  __syncthreads();
  const int i = lane & 31, half = lane >> 5, jb = half * 16;
  const float* Q = q[w];
  const float* K = kk[w];
  float qr[32];
#pragma unroll
  for (int tt = 0; tt < 32; ++tt) qr[tt] = Q[i * 33 + tt];
  float a[16];
#pragma unroll
  for (int j = 0; j < 16; ++j) {
    float s = 0.f;
#pragma unroll
    for (int tt = 0; tt < 32; ++tt) s = fmaf(qr[tt], K[tt * 33 + jb + j], s);
    a[j] = s;
  }
  float mx = a[0];
#pragma unroll
  for (int j = 1; j < 16; ++j) mx = fmaxf(mx, a[j]);
  mx = fmaxf(mx, __shfl_xor(mx, 32));
  float ssum = 0.f;
#pragma unroll
  for (int j = 0; j < 16; ++j) { a[j] = expf(a[j] - mx); ssum += a[j]; }
  ssum += __shfl_xor(ssum, 32);
  float inv = 1.f / ssum;
#pragma unroll
  for (int j = 0; j < 16; ++j) a[j] *= inv;
#pragma unroll
  for (int h = 0; h < 32; ++h) {
    float o = 0.f;
#pragma unroll
    for (int j = 0; j < 16; ++j) o = fmaf(a[j], Q[(jb + j) * 33 + h], o);
    o += __shfl_xor(o, 32);
    if (half == (h >> 4)) kk[w][i * 33 + h] = o;
  }
  __syncthreads();
#pragma unroll
  for (int it = 0; it < 4; ++it) {
    int p = it * 256 + tid;
    int base = (p >> 5) * 33 + (p & 31);
    ushort4 v;
    v.x = f16bits(kk[0][base]);
    v.y = f16bits(kk[1][base]);
    v.z = f16bits(kk[2][base]);
    v.w = f16bits(kk[3][base]);
    *(ushort4*)&aoT[((size_t)b * NP + p) * CDIM + c0] = v;
  }
}

extern "C" void kernel_launch(void* const* d_in, const int* in_sizes, int n_in,
                              void* d_out, int out_size, void* d_ws, size_t ws_size,
                              hipStream_t stream) {
  (void)in_sizes; (void)n_in; (void)out_size; (void)ws_size;
  const float* x = (const float*)d_in[0];
  const float* Ws = (const float*)d_in[1];
  const float* bs = (const float*)d_in[2];
  float* out = (float*)d_out;
  char* ws = (char*)d_ws;

  u16* XT  = (u16*)(ws + XT_OFF);
  u16* hs  = (u16*)(ws + HS_OFF);    // f16 hs11 (z0), hs111 (z1)
  u16* Whi = (u16*)(ws + WHI_OFF);
  u16* aoT = (u16*)(ws + XT_OFF);    // aliases XT (dead after stage-1)

  cast_w_k<<<5184, 256, 0, stream>>>(Ws, Whi);
  transpose_f16_k<<<dim3(32, 24, 32), 256, 0, stream>>>(x, XT);
  // stage-1: hs11 (z=0, W0..3) and hs111 (z=1, W4..7); 256x256 tiles, f16 out
  gemm_p<1, 4><<<dim3(128, 3, 2), 512, 135168, stream>>>(Whi, XT, bs, (void*)hs, 0, 0);
  attn_f_k<<<6144, 256, 0, stream>>>(hs, aoT);
  // final conv: relu(W8 @ attout + b8) -> d_out (fp32)
  gemm_p<0, 1><<<dim3(128, 3, 1), 512, 132096, stream>>>(Whi, aoT, bs, (void*)out, 8, 1);
}